// Round 9
// baseline (561.490 us; speedup 1.0000x reference)
//
#include <hip/hip_runtime.h>

#define Tn 200
#define Dn 64
#define Hn 64
#define CC 16   // pipeline chunk (time steps per LDS buffer)

typedef _Float16 half2v __attribute__((ext_vector_type(2)));
typedef _Float16 half8v __attribute__((ext_vector_type(8)));
typedef unsigned int uint;

__device__ __forceinline__ float fast_sigmoid(float v) {
    return __builtin_amdgcn_rcpf(1.0f + __expf(-v));
}
__device__ __forceinline__ float fast_tanh(float v) {
    return 1.0f - 2.0f * __builtin_amdgcn_rcpf(1.0f + __expf(2.0f * v));
}
// Compiler-only fence (R7-verified): intra-wave DS ordering is HW in-order;
// only compiler reordering must be stopped. No s_waitcnt on the path.
__device__ __forceinline__ void cfence() {
    asm volatile("" ::: "memory");
}
// Producer-side drain: commit ds_writes before signaling the barrier.
__device__ __forceinline__ void lds_drain() {
    asm volatile("s_waitcnt lgkmcnt(0)" ::: "memory");
}
// Raw workgroup barrier with compiler fences (no vmcnt drain — the R6 lesson:
// never let a barrier drain the global-load/store queue).
__device__ __forceinline__ void bar() {
    cfence();
    __builtin_amdgcn_s_barrier();
    cfence();
}

// ============================================================================
// Fused producer/consumer AUGRU. One block per batch row, 2 waves:
//   wave 0 (producer): x-projection P_t = x_t·Wx + bias for a 16-step chunk,
//     fp16-packed into a ping-pong LDS ring.
//   wave 1 (consumer): the R7 recurrence loop, P read from LDS.
// Sync: producer {lds_drain; s_barrier} per chunk; consumer matches barrier
// count (1 prologue + 1 per chunk except the last). Ping-pong buffers.
//
// R8 post-mortem: __launch_bounds__(128,4) starved the allocator to 64 VGPRs
// -> both branches spilled their ~96-VGPR weight arrays to scratch; producer
// became the critical path (FETCH +14 GB, 3870 cyc/step). Fix: (128,2) gives
// a 256-VGPR ceiling; natural allocation (~110) lands under 128, so hardware
// STILL runs 4 waves/SIMD = 16 waves/CU = all 2048 blocks resident, now with
// zero spill. LDS 16.9 KB/block -> 9 blocks/CU limit, above the 8 needed.
// ============================================================================
__global__ __launch_bounds__(128, 2)
void augru_pipe(const float* __restrict__ x,    // [B,T,64]
                const int*   __restrict__ slen, // [B]
                const float* __restrict__ att,  // [B,T]
                const float* __restrict__ gk,   // [128][128]
                const float* __restrict__ gb,   // [128]
                const float* __restrict__ ck,   // [128][64]
                const float* __restrict__ cb,   // [64]
                float*       __restrict__ out)  // [B,T,64]
{
    const int b    = blockIdx.x;
    const int tid  = threadIdx.x;
    const int wave = tid >> 6;
    const int j    = tid & 63;

    __shared__ __align__(16) _Float16 sP[2][CC][Hn][4];  // {pr,pu,pc,pad} fp16
    __shared__ __align__(16) _Float16 s_h[Hn];
    __shared__ __align__(16) _Float16 s_rh[Hn];

    const int len = slen[b];
    const int nch = (len + CC - 1) / CC;
    const float* xrow = x   + (size_t)b * Tn * Dn;
    const float* arow = att + (size_t)b * Tn;
    float*       orow = out + (size_t)b * Tn * Hn;

    if (wave == 0) {
        // ---------------- producer: x-part weights (K rows 0..63) ----------
        half2v wr[32], wu[32], wc[32];
#pragma unroll
        for (int m = 0; m < 32; ++m) {
            const int k = 2 * m;
            wr[m] = half2v{(_Float16)gk[(k + 0) * 128 + j],
                           (_Float16)gk[(k + 1) * 128 + j]};
            wu[m] = half2v{(_Float16)gk[(k + 0) * 128 + 64 + j],
                           (_Float16)gk[(k + 1) * 128 + 64 + j]};
            wc[m] = half2v{(_Float16)ck[(k + 0) * 64 + j],
                           (_Float16)ck[(k + 1) * 64 + j]};
        }
        const float br = gb[j], bu = gb[64 + j], bc = cb[j];

        for (int p = 0; p < nch; ++p) {
            const int t0 = p * CC, tend = min(len, t0 + CC);
            for (int t = t0; t < tend; ++t) {
                const float4* xv = (const float4*)(xrow + t * Dn);
                float r0 = br, r1 = 0.f, u0 = bu, u1 = 0.f, c0 = bc, c1 = 0.f;
#pragma unroll
                for (int kk = 0; kk < 16; ++kk) {
                    const float4 qx = xv[kk];
                    const half2v p0 = half2v{(_Float16)qx.x, (_Float16)qx.y};
                    const half2v p1 = half2v{(_Float16)qx.z, (_Float16)qx.w};
                    const int m = 2 * kk;
                    r0 = __builtin_amdgcn_fdot2(p0, wr[m],     r0, false);
                    r1 = __builtin_amdgcn_fdot2(p1, wr[m + 1], r1, false);
                    u0 = __builtin_amdgcn_fdot2(p0, wu[m],     u0, false);
                    u1 = __builtin_amdgcn_fdot2(p1, wu[m + 1], u1, false);
                    c0 = __builtin_amdgcn_fdot2(p0, wc[m],     c0, false);
                    c1 = __builtin_amdgcn_fdot2(p1, wc[m + 1], c1, false);
                }
                const half2v d0{(_Float16)(r0 + r1), (_Float16)(u0 + u1)};
                const half2v d1{(_Float16)(c0 + c1), (_Float16)0.0f};
                uint2 pk;
                pk.x = __builtin_bit_cast(uint, d0);
                pk.y = __builtin_bit_cast(uint, d1);
                *(uint2*)&sP[p & 1][t - t0][j][0] = pk;   // ds_write_b64
            }
            lds_drain();   // commit chunk p before signaling
            bar();
        }
    } else {
        // ---------------- consumer: h-part weights (K rows 64..127) --------
        half2v wr[32], wu[32], wc[32];
#pragma unroll
        for (int m = 0; m < 32; ++m) {
            const int k = 64 + 2 * m;
            wr[m] = half2v{(_Float16)gk[(k + 0) * 128 + j],
                           (_Float16)gk[(k + 1) * 128 + j]};
            wu[m] = half2v{(_Float16)gk[(k + 0) * 128 + 64 + j],
                           (_Float16)gk[(k + 1) * 128 + 64 + j]};
            wc[m] = half2v{(_Float16)ck[(k + 0) * 64 + j],
                           (_Float16)ck[(k + 1) * 64 + j]};
        }

        float h   = 0.0f;
        float a_n = (len > 0) ? arow[0] : 0.0f;   // 1-step att prefetch

        if (nch > 0) {
            bar();   // chunk 0 ready
            for (int p = 0; p < nch; ++p) {
                const int t0 = p * CC, tend = min(len, t0 + CC);
                for (int t = t0; t < tend; ++t) {
                    const float a = a_n;
                    a_n = arow[min(t + 1, len - 1)];

                    s_h[j] = (_Float16)h;
                    cfence();
                    // P read issues into the DS pipe behind the s_h write;
                    // data returns alongside the h-broadcast reads -> free.
                    const uint2 q = *(const uint2*)&sP[p & 1][t - t0][j][0];
                    const half2v g0 = __builtin_bit_cast(half2v, q.x);
                    const half2v g1 = __builtin_bit_cast(half2v, q.y);

                    float r0 = (float)g0[0], r1 = 0.f;
                    float u0 = (float)g0[1], u1 = 0.f;
                    const float pc = (float)g1[0];

                    const half8v* hv = (const half8v*)s_h;
#pragma unroll
                    for (int m8 = 0; m8 < 8; ++m8) {
                        const half8v v = hv[m8];
                        const half2v p0 = __builtin_shufflevector(v, v, 0, 1);
                        const half2v p1 = __builtin_shufflevector(v, v, 2, 3);
                        const half2v p2 = __builtin_shufflevector(v, v, 4, 5);
                        const half2v p3 = __builtin_shufflevector(v, v, 6, 7);
                        const int m = m8 * 4;
                        r0 = __builtin_amdgcn_fdot2(p0, wr[m + 0], r0, false);
                        r1 = __builtin_amdgcn_fdot2(p1, wr[m + 1], r1, false);
                        r0 = __builtin_amdgcn_fdot2(p2, wr[m + 2], r0, false);
                        r1 = __builtin_amdgcn_fdot2(p3, wr[m + 3], r1, false);
                        u0 = __builtin_amdgcn_fdot2(p0, wu[m + 0], u0, false);
                        u1 = __builtin_amdgcn_fdot2(p1, wu[m + 1], u1, false);
                        u0 = __builtin_amdgcn_fdot2(p2, wu[m + 2], u0, false);
                        u1 = __builtin_amdgcn_fdot2(p3, wu[m + 3], u1, false);
                    }
                    const float rg = fast_sigmoid(r0 + r1);
                    const float ug = fast_sigmoid(u0 + u1);

                    s_rh[j] = (_Float16)(rg * h);
                    cfence();

                    float c0 = pc, c1 = 0.f;
                    const half8v* rv = (const half8v*)s_rh;
#pragma unroll
                    for (int m8 = 0; m8 < 8; ++m8) {
                        const half8v v = rv[m8];
                        const half2v p0 = __builtin_shufflevector(v, v, 0, 1);
                        const half2v p1 = __builtin_shufflevector(v, v, 2, 3);
                        const half2v p2 = __builtin_shufflevector(v, v, 4, 5);
                        const half2v p3 = __builtin_shufflevector(v, v, 6, 7);
                        const int m = m8 * 4;
                        c0 = __builtin_amdgcn_fdot2(p0, wc[m + 0], c0, false);
                        c1 = __builtin_amdgcn_fdot2(p1, wc[m + 1], c1, false);
                        c0 = __builtin_amdgcn_fdot2(p2, wc[m + 2], c0, false);
                        c1 = __builtin_amdgcn_fdot2(p3, wc[m + 3], c1, false);
                    }
                    const float cg = fast_tanh(c0 + c1);

                    const float uh = (1.0f - a) * ug;
                    h = uh * h + (1.0f - uh) * cg;
                    orow[t * Hn + j] = h;
                    cfence();   // WAR vs next step's s_h/s_rh writes
                }
                if (p < nch - 1) bar();   // next chunk ready (matches producer)
            }
        }
    }

    // ---- zero tail: out[b, len:T, :] = 0 (both waves) ----
    float4 z;
    z.x = z.y = z.z = z.w = 0.0f;
    float* tail = orow + (size_t)len * Hn;
    const int total = (Tn - len) * Hn;
    for (int i = tid * 4; i < total; i += 128 * 4) {
        *(float4*)(tail + i) = z;
    }
}

extern "C" void kernel_launch(void* const* d_in, const int* in_sizes, int n_in,
                              void* d_out, int out_size, void* d_ws, size_t ws_size,
                              hipStream_t stream) {
    const float* x    = (const float*)d_in[0];
    const int*   slen = (const int*)  d_in[1];
    const float* att  = (const float*)d_in[2];
    const float* gk   = (const float*)d_in[3];
    const float* gb   = (const float*)d_in[4];
    const float* ck   = (const float*)d_in[5];
    const float* cb   = (const float*)d_in[6];
    float* out = (float*)d_out;

    const int B = in_sizes[1];  // 2048
    augru_pipe<<<B, 128, 0, stream>>>(x, slen, att, gk, gb, ck, cb, out);
}

// Round 10
// 419.911 us; speedup vs baseline: 1.3372x; 1.3372x over previous
//
#include <hip/hip_runtime.h>

#define Tn 200
#define Dn 64
#define Hn 64
#define CC 16   // chunk: time steps per LDS proj buffer

typedef _Float16 half2v __attribute__((ext_vector_type(2)));
typedef _Float16 half8v __attribute__((ext_vector_type(8)));
typedef unsigned int uint;

__device__ __forceinline__ float fast_sigmoid(float v) {
    return __builtin_amdgcn_rcpf(1.0f + __expf(-v));
}
__device__ __forceinline__ float fast_tanh(float v) {
    return 1.0f - 2.0f * __builtin_amdgcn_rcpf(1.0f + __expf(2.0f * v));
}
__device__ __forceinline__ uint pk16(float a, float b) {   // cvt_pkrtz pack
    return __builtin_bit_cast(uint, __builtin_amdgcn_cvt_pkrtz(a, b));
}
// Compiler-only fence (R7-verified +5%): intra-wave DS ordering is HW in-order;
// only compiler reordering must be stopped. No s_waitcnt on the path.
__device__ __forceinline__ void cfence() {
    asm volatile("" ::: "memory");
}

// ============================================================================
// Monolithic single-wave AUGRU (R10). One block = one wave = one batch row.
// Per 16-step chunk, the SAME wave alternates:
//   stage: 4 coalesced dwordx4 -> cvt_pk -> x-chunk fp16 in LDS (2 KB)
//          (next chunk's loads are ISSUED before the rec phase -> HBM latency
//           hides under ~27k cycles of recurrence; T14 split)
//   proj : per t, 8x ds_read_b128 (uniform/broadcast) + 96 fdot2 -> P_t
//          packed fp16 {pr,pu,pc} into LDS sLP (8 KB)
//   rec  : R7 recurrence body, P from LDS (1 ds_read_b64/step)
// Same-wave => DS in-order => NO barriers, NO s_waitcnt on the critical path.
// No workspace, no second kernel, no P HBM traffic.
// Register budget: 192 (both weight sets) + ~50 working ~= 240 < 256
//   => launch_bounds(64,2): 2 waves/SIMD, all 2048 rows resident from t=0.
// LDS: 2 + 8 + 0.25 KB ~= 10.4 KB/block; 8 blocks/CU -> 83 KB/CU. OK.
// ============================================================================
__global__ __launch_bounds__(64, 2)
void augru_mono(const float* __restrict__ x,    // [B,T,64]
                const int*   __restrict__ slen, // [B]
                const float* __restrict__ att,  // [B,T]
                const float* __restrict__ gk,   // [128][128]
                const float* __restrict__ gb,   // [128]
                const float* __restrict__ ck,   // [128][64]
                const float* __restrict__ cb,   // [64]
                float*       __restrict__ out)  // [B,T,64]
{
    const int b = blockIdx.x;
    const int j = threadIdx.x;

    __shared__ __align__(16) uint  s_x[CC * 32];     // x chunk fp16 [CC][64]
    __shared__ __align__(16) uint2 sLP[CC][Hn];      // P chunk {pr,pu}{pc,_}
    __shared__ __align__(16) _Float16 s_h[Hn];
    __shared__ __align__(16) _Float16 s_rh[Hn];

    const int len = slen[b];
    const float* xrow = x   + (size_t)b * Tn * Dn;
    const float* arow = att + (size_t)b * Tn;
    float*       orow = out + (size_t)b * Tn * Hn;

    if (len > 0) {
        const int nch = (len + CC - 1) / CC;

        // ---- both weight sets, persistent in registers ----
        half2v wrx[32], wux[32], wcx[32];   // x-part (K rows 0..63)
        half2v wrh[32], wuh[32], wch[32];   // h-part (K rows 64..127)
#pragma unroll
        for (int m = 0; m < 32; ++m) {
            const int kx = 2 * m, kh = 64 + 2 * m;
            wrx[m] = half2v{(_Float16)gk[(kx + 0) * 128 + j],
                            (_Float16)gk[(kx + 1) * 128 + j]};
            wux[m] = half2v{(_Float16)gk[(kx + 0) * 128 + 64 + j],
                            (_Float16)gk[(kx + 1) * 128 + 64 + j]};
            wcx[m] = half2v{(_Float16)ck[(kx + 0) * 64 + j],
                            (_Float16)ck[(kx + 1) * 64 + j]};
            wrh[m] = half2v{(_Float16)gk[(kh + 0) * 128 + j],
                            (_Float16)gk[(kh + 1) * 128 + j]};
            wuh[m] = half2v{(_Float16)gk[(kh + 0) * 128 + 64 + j],
                            (_Float16)gk[(kh + 1) * 128 + 64 + j]};
            wch[m] = half2v{(_Float16)ck[(kh + 0) * 64 + j],
                            (_Float16)ck[(kh + 1) * 64 + j]};
        }
        const float br = gb[j], bu = gb[64 + j], bc = cb[j];

        // ---- staging regs + helpers ----
        const int lt4 = j >> 4;          // staged sub-row 0..3 within group of 4
        const int c2  = (j & 15) * 2;    // LDS dword col
        const int xmax = Tn * Dn - 4;    // clamp: stay inside this row's x
        float4 st0, st1, st2, st3;

        // stage chunk 0: issue + write
        {
            const int base = 4 * j;
            st0 = *(const float4*)(xrow + min(base +   0, xmax));
            st1 = *(const float4*)(xrow + min(base + 256, xmax));
            st2 = *(const float4*)(xrow + min(base + 512, xmax));
            st3 = *(const float4*)(xrow + min(base + 768, xmax));
        }
        {
            uint2 w;
            w.x = pk16(st0.x, st0.y); w.y = pk16(st0.z, st0.w);
            *(uint2*)&s_x[(0 + lt4) * 32 + c2] = w;
            w.x = pk16(st1.x, st1.y); w.y = pk16(st1.z, st1.w);
            *(uint2*)&s_x[(4 + lt4) * 32 + c2] = w;
            w.x = pk16(st2.x, st2.y); w.y = pk16(st2.z, st2.w);
            *(uint2*)&s_x[(8 + lt4) * 32 + c2] = w;
            w.x = pk16(st3.x, st3.y); w.y = pk16(st3.z, st3.w);
            *(uint2*)&s_x[(12 + lt4) * 32 + c2] = w;
        }
        cfence();

        float h   = 0.0f;
        float a_n = arow[0];   // 1-step att prefetch

        for (int p = 0; p < nch; ++p) {
            const int t0 = p * CC, tend = min(len, t0 + CC);

            // ---------- proj phase: P_t for this chunk into sLP ----------
            for (int t = t0; t < tend; ++t) {
                const int lt = t - t0;
                const half8v* xv = (const half8v*)&s_x[lt * 32];
                float r0 = br, r1 = 0.f, u0 = bu, u1 = 0.f, c0 = bc, c1 = 0.f;
#pragma unroll
                for (int m8 = 0; m8 < 8; ++m8) {
                    const half8v v = xv[m8];
                    const half2v p0 = __builtin_shufflevector(v, v, 0, 1);
                    const half2v p1 = __builtin_shufflevector(v, v, 2, 3);
                    const half2v p2 = __builtin_shufflevector(v, v, 4, 5);
                    const half2v p3 = __builtin_shufflevector(v, v, 6, 7);
                    const int m = m8 * 4;
                    r0 = __builtin_amdgcn_fdot2(p0, wrx[m + 0], r0, false);
                    r1 = __builtin_amdgcn_fdot2(p1, wrx[m + 1], r1, false);
                    r0 = __builtin_amdgcn_fdot2(p2, wrx[m + 2], r0, false);
                    r1 = __builtin_amdgcn_fdot2(p3, wrx[m + 3], r1, false);
                    u0 = __builtin_amdgcn_fdot2(p0, wux[m + 0], u0, false);
                    u1 = __builtin_amdgcn_fdot2(p1, wux[m + 1], u1, false);
                    u0 = __builtin_amdgcn_fdot2(p2, wux[m + 2], u0, false);
                    u1 = __builtin_amdgcn_fdot2(p3, wux[m + 3], u1, false);
                    c0 = __builtin_amdgcn_fdot2(p0, wcx[m + 0], c0, false);
                    c1 = __builtin_amdgcn_fdot2(p1, wcx[m + 1], c1, false);
                    c0 = __builtin_amdgcn_fdot2(p2, wcx[m + 2], c0, false);
                    c1 = __builtin_amdgcn_fdot2(p3, wcx[m + 3], c1, false);
                }
                // pack P with RTN casts (R8-verified numerics)
                const half2v d0{(_Float16)(r0 + r1), (_Float16)(u0 + u1)};
                const half2v d1{(_Float16)(c0 + c1), (_Float16)0.0f};
                uint2 pk;
                pk.x = __builtin_bit_cast(uint, d0);
                pk.y = __builtin_bit_cast(uint, d1);
                *(uint2*)&sLP[lt][j] = pk;
            }
            cfence();

            // ---------- issue next chunk's x loads (hide under rec) ----------
            const bool more = (p + 1 < nch);
            if (more) {
                const int base = (t0 + CC) * Dn + 4 * j;
                st0 = *(const float4*)(xrow + min(base +   0, xmax));
                st1 = *(const float4*)(xrow + min(base + 256, xmax));
                st2 = *(const float4*)(xrow + min(base + 512, xmax));
                st3 = *(const float4*)(xrow + min(base + 768, xmax));
            }

            // ---------- rec phase (R7 body, P from LDS) ----------
            for (int t = t0; t < tend; ++t) {
                const float a = a_n;
                a_n = arow[min(t + 1, len - 1)];

                s_h[j] = (_Float16)h;
                cfence();
                // P read issues into the DS pipe behind the s_h write
                const uint2 q = *(const uint2*)&sLP[t - t0][j];
                const half2v g0 = __builtin_bit_cast(half2v, q.x);
                const half2v g1 = __builtin_bit_cast(half2v, q.y);

                float r0 = (float)g0[0], r1 = 0.f;
                float u0 = (float)g0[1], u1 = 0.f;
                const float pc = (float)g1[0];

                const half8v* hv = (const half8v*)s_h;
#pragma unroll
                for (int m8 = 0; m8 < 8; ++m8) {
                    const half8v v = hv[m8];
                    const half2v p0 = __builtin_shufflevector(v, v, 0, 1);
                    const half2v p1 = __builtin_shufflevector(v, v, 2, 3);
                    const half2v p2 = __builtin_shufflevector(v, v, 4, 5);
                    const half2v p3 = __builtin_shufflevector(v, v, 6, 7);
                    const int m = m8 * 4;
                    r0 = __builtin_amdgcn_fdot2(p0, wrh[m + 0], r0, false);
                    r1 = __builtin_amdgcn_fdot2(p1, wrh[m + 1], r1, false);
                    r0 = __builtin_amdgcn_fdot2(p2, wrh[m + 2], r0, false);
                    r1 = __builtin_amdgcn_fdot2(p3, wrh[m + 3], r1, false);
                    u0 = __builtin_amdgcn_fdot2(p0, wuh[m + 0], u0, false);
                    u1 = __builtin_amdgcn_fdot2(p1, wuh[m + 1], u1, false);
                    u0 = __builtin_amdgcn_fdot2(p2, wuh[m + 2], u0, false);
                    u1 = __builtin_amdgcn_fdot2(p3, wuh[m + 3], u1, false);
                }
                const float rg = fast_sigmoid(r0 + r1);
                const float ug = fast_sigmoid(u0 + u1);

                s_rh[j] = (_Float16)(rg * h);
                cfence();

                float c0 = pc, c1 = 0.f;
                const half8v* rv = (const half8v*)s_rh;
#pragma unroll
                for (int m8 = 0; m8 < 8; ++m8) {
                    const half8v v = rv[m8];
                    const half2v p0 = __builtin_shufflevector(v, v, 0, 1);
                    const half2v p1 = __builtin_shufflevector(v, v, 2, 3);
                    const half2v p2 = __builtin_shufflevector(v, v, 4, 5);
                    const half2v p3 = __builtin_shufflevector(v, v, 6, 7);
                    const int m = m8 * 4;
                    c0 = __builtin_amdgcn_fdot2(p0, wch[m + 0], c0, false);
                    c1 = __builtin_amdgcn_fdot2(p1, wch[m + 1], c1, false);
                    c0 = __builtin_amdgcn_fdot2(p2, wch[m + 2], c0, false);
                    c1 = __builtin_amdgcn_fdot2(p3, wch[m + 3], c1, false);
                }
                const float cg = fast_tanh(c0 + c1);

                const float uh = (1.0f - a) * ug;
                h = uh * h + (1.0f - uh) * cg;
                orow[t * Hn + j] = h;
                cfence();   // WAR vs next step's s_h/s_rh writes
            }

            // ---------- write staged x for next chunk (loads long since done) ----
            if (more) {
                uint2 w;
                w.x = pk16(st0.x, st0.y); w.y = pk16(st0.z, st0.w);
                *(uint2*)&s_x[(0 + lt4) * 32 + c2] = w;
                w.x = pk16(st1.x, st1.y); w.y = pk16(st1.z, st1.w);
                *(uint2*)&s_x[(4 + lt4) * 32 + c2] = w;
                w.x = pk16(st2.x, st2.y); w.y = pk16(st2.z, st2.w);
                *(uint2*)&s_x[(8 + lt4) * 32 + c2] = w;
                w.x = pk16(st3.x, st3.y); w.y = pk16(st3.z, st3.w);
                *(uint2*)&s_x[(12 + lt4) * 32 + c2] = w;
                cfence();
            }
        }
    }

    // ---- zero tail: out[b, len:T, :] = 0 ----
    float4 z;
    z.x = z.y = z.z = z.w = 0.0f;
    float* tail = orow + (size_t)len * Hn;
    const int total = (Tn - len) * Hn;
    for (int i = j * 4; i < total; i += 64 * 4) {
        *(float4*)(tail + i) = z;
    }
}

extern "C" void kernel_launch(void* const* d_in, const int* in_sizes, int n_in,
                              void* d_out, int out_size, void* d_ws, size_t ws_size,
                              hipStream_t stream) {
    const float* x    = (const float*)d_in[0];
    const int*   slen = (const int*)  d_in[1];
    const float* att  = (const float*)d_in[2];
    const float* gk   = (const float*)d_in[3];
    const float* gb   = (const float*)d_in[4];
    const float* ck   = (const float*)d_in[5];
    const float* cb   = (const float*)d_in[6];
    float* out = (float*)d_out;

    const int B = in_sizes[1];  // 2048
    augru_mono<<<B, 64, 0, stream>>>(x, slen, att, gk, gb, ck, cb, out);
}